// Round 5
// baseline (202.957 us; speedup 1.0000x reference)
//
#include <hip/hip_runtime.h>
#include <hip/hip_bf16.h>

#define HW  16384
#define WD  128
#define MNS 16448          // padded bf16 channel stride (16384+64)

#define TCY 8              // center rows per tile
#define TCX 16             // center cols per tile
#define HRY 10             // halo rows
#define HRX 18             // halo cols
#define HPX 180            // halo pixels
#define PRS 20             // padded halo row stride (slots)
#define PLS 200            // plane stride per o4 (ushort4 slots)

__device__ __forceinline__ unsigned short f2bf(float f) {
    unsigned int u = __builtin_bit_cast(unsigned int, f);
    u += 0x7FFFu + ((u >> 16) & 1u);          // RNE
    return (unsigned short)(u >> 16);
}
__device__ __forceinline__ float bf2f(unsigned short s) {
    return __builtin_bit_cast(float, (unsigned int)s << 16);
}

// ---- k1: x -> mn (80 ch, bf16), 1 px/thread --------------------------------
__global__ __launch_bounds__(256) void la_k1(
    const float* __restrict__ x,
    const float* __restrict__ w1, const float* __restrict__ b1,
    const float* __restrict__ g1, const float* __restrict__ be1,
    const float* __restrict__ m1, const float* __restrict__ v1,
    const float* __restrict__ w2, const float* __restrict__ b2,
    const float* __restrict__ g2, const float* __restrict__ be2,
    const float* __restrict__ m2, const float* __restrict__ v2,
    unsigned short* __restrict__ mn)
{
    const int pix = blockIdx.x * blockDim.x + threadIdx.x;   // 0..16383
    const int bg  = blockIdx.y;
    const int b   = bg >> 3, g = bg & 7;

    const float* xp = x + (size_t)(b * 256 + g * 32) * HW + pix;
    float xg[32];
#pragma unroll
    for (int c = 0; c < 32; ++c) xg[c] = xp[(size_t)c * HW];

    float t[8];
    const float* w1g = w1 + g * 256;
#pragma unroll
    for (int o = 0; o < 8; ++o) {
        float a = 0.f;
#pragma unroll
        for (int ci = 0; ci < 32; ++ci) a = fmaf(xg[ci], w1g[o * 32 + ci], a);
        const int ch = g * 8 + o;
        const float inv = g1[ch] * rsqrtf(v1[ch] + 1e-5f);
        const float add = be1[ch] + (b1[ch] - m1[ch]) * inv;
        t[o] = tanhf(fmaf(a, inv, add));
    }

    const float* w2g = w2 + g * 80;
    unsigned short* mnp = mn + (size_t)(b * 80 + g * 10) * MNS + pix;
#pragma unroll
    for (int o = 0; o < 10; ++o) {
        float a = 0.f;
#pragma unroll
        for (int i = 0; i < 8; ++i) a = fmaf(t[i], w2g[o * 8 + i], a);
        const int ch = g * 10 + o;
        const float inv = g2[ch] * rsqrtf(v2[ch] + 1e-5f);
        const float add = be2[ch] + (b2[ch] - m2[ch]) * inv;
        mnp[(size_t)o * MNS] = f2bf(fmaf(a, inv, add));
    }
}

// ---- k2: fused v-conv (bf16 LDS) + softmax attention + PV ------------------
__global__ __launch_bounds__(256, 8) void la_k2(
    const float* __restrict__ x, const float* __restrict__ wv,
    const unsigned short* __restrict__ mn, float* __restrict__ out)
{
    __shared__ ushort4 vt[8 * PLS];            // 12800 B

    const int tid  = threadIdx.x;
    const int tile = blockIdx.x;               // 0..127
    const int bg   = blockIdx.y;
    const int b    = bg >> 3, g = bg & 7;
    const int ty0  = (tile >> 3) * TCY;
    const int tx0  = (tile & 7) * TCX;

    // ---- phase 1: one halo pixel per thread (tid < 180) ----
    if (tid < HPX) {
        const int hy = tid / HRX, hx = tid - hy * HRX;
        const int iy = ty0 + hy - 1, ix = tx0 + hx - 1;
        const int slot = hy * PRS + hx;
        if (((unsigned)iy < 128u) && ((unsigned)ix < 128u)) {
            const float* xp  = x  + (size_t)(b * 256 + g * 32) * HW + iy * WD + ix;
            const float* wvg = wv + g * 1024;
            float xv[32];
#pragma unroll
            for (int c = 0; c < 32; ++c) xv[c] = xp[(size_t)c * HW];
#pragma unroll
            for (int o4 = 0; o4 < 8; ++o4) {
                float a0 = 0.f, a1 = 0.f, a2 = 0.f, a3 = 0.f;
                const float* wp = wvg + o4 * 128;
#pragma unroll
                for (int c = 0; c < 32; ++c) {
                    const float xc = xv[c];
                    a0 = fmaf(xc, wp[c],      a0);
                    a1 = fmaf(xc, wp[32 + c], a1);
                    a2 = fmaf(xc, wp[64 + c], a2);
                    a3 = fmaf(xc, wp[96 + c], a3);
                }
                vt[o4 * PLS + slot] = make_ushort4(f2bf(a0), f2bf(a1), f2bf(a2), f2bf(a3));
            }
        } else {
            const ushort4 z = make_ushort4(0, 0, 0, 0);
#pragma unroll
            for (int o4 = 0; o4 < 8; ++o4) vt[o4 * PLS + slot] = z;
        }
    }
    __syncthreads();

    // ---- phase 2: 2 threads per center pixel, 16 channels each ----
    const int px  = tid & 127;
    const int cy  = px >> 4, cx = px & 15;
    const int ob  = (tid >> 7) * 4;            // o4 base: 0 or 4
    const int iy  = ty0 + cy, ix = tx0 + cx;
    const int pix = iy * WD + ix;

    const unsigned short* nbp = mn + (size_t)(b * 80 + g) * MNS;
    const unsigned short* mkp = mn + (size_t)(b * 80 + 8 + g * 9) * MNS + pix;

    float lg[9];
    float mx = -1e30f;
#pragma unroll
    for (int k = 0; k < 9; ++k) {
        const int dy = k / 3 - 1, dx = k % 3 - 1;
        const int ny = iy + dy, nx = ix + dx;
        const bool ok = ((unsigned)ny < 128u) && ((unsigned)nx < 128u);
        const float nb = ok ? bf2f(nbp[ny * WD + nx]) : 0.f;
        lg[k] = bf2f(mkp[(size_t)k * MNS]) + nb;
        mx = fmaxf(mx, lg[k]);
    }
    float s = 0.f;
#pragma unroll
    for (int k = 0; k < 9; ++k) { lg[k] = __expf(lg[k] - mx); s += lg[k]; }
    const float rs = 1.f / s;
#pragma unroll
    for (int k = 0; k < 9; ++k) lg[k] *= rs;   // OOB taps hit v==0 in LDS

    float* og = out + (size_t)(b * 256 + g * 32 + ob * 4) * HW + pix;
#pragma unroll
    for (int u = 0; u < 4; ++u) {
        const ushort4* vp = vt + (ob + u) * PLS;
        float a0 = 0.f, a1 = 0.f, a2 = 0.f, a3 = 0.f;
#pragma unroll
        for (int k = 0; k < 9; ++k) {
            const int slot = (cy + k / 3) * PRS + (cx + k % 3);
            const ushort4 vv = vp[slot];
            a0 = fmaf(lg[k], bf2f(vv.x), a0);
            a1 = fmaf(lg[k], bf2f(vv.y), a1);
            a2 = fmaf(lg[k], bf2f(vv.z), a2);
            a3 = fmaf(lg[k], bf2f(vv.w), a3);
        }
        og[(size_t)(u * 4 + 0) * HW] = a0;
        og[(size_t)(u * 4 + 1) * HW] = a1;
        og[(size_t)(u * 4 + 2) * HW] = a2;
        og[(size_t)(u * 4 + 3) * HW] = a3;
    }
}

extern "C" void kernel_launch(void* const* d_in, const int* in_sizes, int n_in,
                              void* d_out, int out_size, void* d_ws, size_t ws_size,
                              hipStream_t stream)
{
    const float* x   = (const float*)d_in[0];
    const float* w1  = (const float*)d_in[1];
    const float* b1  = (const float*)d_in[2];
    const float* g1  = (const float*)d_in[3];
    const float* be1 = (const float*)d_in[4];
    const float* m1  = (const float*)d_in[5];
    const float* v1  = (const float*)d_in[6];
    const float* w2  = (const float*)d_in[7];
    const float* b2  = (const float*)d_in[8];
    const float* g2  = (const float*)d_in[9];
    const float* be2 = (const float*)d_in[10];
    const float* m2  = (const float*)d_in[11];
    const float* v2  = (const float*)d_in[12];
    const float* wv  = (const float*)d_in[13];

    float* out = (float*)d_out;
    unsigned short* mn = (unsigned short*)d_ws;   // 2*80*MNS bf16 = 5.3 MB

    dim3 blk(256);
    dim3 g1d(HW / 256, 16);        // 1024 blocks
    dim3 g2d(128, 16);             // 128 tiles (16 row x 8 col) x 16 bg = 2048 blocks

    hipLaunchKernelGGL(la_k1, g1d, blk, 0, stream,
                       x, w1, b1, g1, be1, m1, v1, w2, b2, g2, be2, m2, v2, mn);
    hipLaunchKernelGGL(la_k2, g2d, blk, 0, stream, x, wv, mn, out);
}

// Round 6
// 134.115 us; speedup vs baseline: 1.5133x; 1.5133x over previous
//
#include <hip/hip_runtime.h>
#include <hip/hip_bf16.h>

#define HW  16384
#define WD  128
#define MNS 16448          // padded bf16 channel stride (16384+64)

#define TS   16            // center tile side
#define HS   18            // halo side
#define HP   (HS * HS)     // 324 halo pixels
#define PRS  20            // padded halo row stride (ushort4 slots)
#define PLS  360           // plane stride per o4 (ushort4 slots) = 18*20

__device__ __forceinline__ unsigned short f2bf(float f) {
    unsigned int u = __builtin_bit_cast(unsigned int, f);
    u += 0x7FFFu + ((u >> 16) & 1u);          // RNE
    return (unsigned short)(u >> 16);
}
__device__ __forceinline__ float bf2f(unsigned short s) {
    return __builtin_bit_cast(float, (unsigned int)s << 16);
}

// ---- k1: x -> mn (80 ch, bf16), 1 px/thread --------------------------------
__global__ __launch_bounds__(256) void la_k1(
    const float* __restrict__ x,
    const float* __restrict__ w1, const float* __restrict__ b1,
    const float* __restrict__ g1, const float* __restrict__ be1,
    const float* __restrict__ m1, const float* __restrict__ v1,
    const float* __restrict__ w2, const float* __restrict__ b2,
    const float* __restrict__ g2, const float* __restrict__ be2,
    const float* __restrict__ m2, const float* __restrict__ v2,
    unsigned short* __restrict__ mn)
{
    const int pix = blockIdx.x * blockDim.x + threadIdx.x;   // 0..16383
    const int bg  = blockIdx.y;
    const int b   = bg >> 3, g = bg & 7;

    const float* xp = x + (size_t)(b * 256 + g * 32) * HW + pix;
    float xg[32];
#pragma unroll
    for (int c = 0; c < 32; ++c) xg[c] = xp[(size_t)c * HW];

    float t[8];
    const float* w1g = w1 + g * 256;
#pragma unroll
    for (int o = 0; o < 8; ++o) {
        float a = 0.f;
#pragma unroll
        for (int ci = 0; ci < 32; ++ci) a = fmaf(xg[ci], w1g[o * 32 + ci], a);
        const int ch = g * 8 + o;
        const float inv = g1[ch] * rsqrtf(v1[ch] + 1e-5f);
        const float add = be1[ch] + (b1[ch] - m1[ch]) * inv;
        t[o] = tanhf(fmaf(a, inv, add));
    }

    const float* w2g = w2 + g * 80;
    unsigned short* mnp = mn + (size_t)(b * 80 + g * 10) * MNS + pix;
#pragma unroll
    for (int o = 0; o < 10; ++o) {
        float a = 0.f;
#pragma unroll
        for (int i = 0; i < 8; ++i) a = fmaf(t[i], w2g[o * 8 + i], a);
        const int ch = g * 10 + o;
        const float inv = g2[ch] * rsqrtf(v2[ch] + 1e-5f);
        const float add = be2[ch] + (b2[ch] - m2[ch]) * inv;
        mnp[(size_t)o * MNS] = f2bf(fmaf(a, inv, add));
    }
}

// ---- k2: fused v-conv (bf16 LDS) + softmax attention + PV ------------------
// grid = (16 bg, 64 tiles): linear block id % 8 == g -> per-XCD x locality
__global__ __launch_bounds__(256) void la_k2(
    const float* __restrict__ x, const float* __restrict__ wv,
    const unsigned short* __restrict__ mn, float* __restrict__ out)
{
    __shared__ ushort4 vt[8 * PLS];            // 23040 B

    const int tid  = threadIdx.x;
    const int bg   = blockIdx.x;
    const int tile = blockIdx.y;               // 0..63
    const int b    = bg >> 3, g = bg & 7;
    const int ty0  = (tile >> 3) * TS;
    const int tx0  = (tile & 7) * TS;

    const float* xg  = x  + (size_t)(b * 256 + g * 32) * HW;
    const float* wvg = wv + g * 1024;

    // ---- phase 1: v = Wv*x on the 18x18 halo -> bf16 LDS (0 outside) ----
    for (int hp = tid; hp < HP; hp += 256) {
        const int hy = hp / HS, hx = hp - hy * HS;
        const int iy = ty0 + hy - 1, ix = tx0 + hx - 1;
        const int slot = hy * PRS + hx;
        if (((unsigned)iy < 128u) && ((unsigned)ix < 128u)) {
            const float* xp = xg + iy * WD + ix;
            float xv[32];
#pragma unroll
            for (int c = 0; c < 32; ++c) xv[c] = xp[(size_t)c * HW];
#pragma unroll
            for (int o4 = 0; o4 < 8; ++o4) {
                float a0 = 0.f, a1 = 0.f, a2 = 0.f, a3 = 0.f;
                const float* wp = wvg + o4 * 128;
#pragma unroll
                for (int c = 0; c < 32; ++c) {
                    const float xc = xv[c];
                    a0 = fmaf(xc, wp[c],      a0);
                    a1 = fmaf(xc, wp[32 + c], a1);
                    a2 = fmaf(xc, wp[64 + c], a2);
                    a3 = fmaf(xc, wp[96 + c], a3);
                }
                vt[o4 * PLS + slot] = make_ushort4(f2bf(a0), f2bf(a1), f2bf(a2), f2bf(a3));
            }
        } else {
            const ushort4 z = make_ushort4(0, 0, 0, 0);
#pragma unroll
            for (int o4 = 0; o4 < 8; ++o4) vt[o4 * PLS + slot] = z;
        }
    }
    __syncthreads();

    // ---- phase 2: one center pixel per thread, all 32 channels ----
    const int cy  = tid >> 4, cx = tid & 15;
    const int iy  = ty0 + cy, ix = tx0 + cx;
    const int pix = iy * WD + ix;

    const unsigned short* nbp = mn + (size_t)(b * 80 + g) * MNS;
    const unsigned short* mkp = mn + (size_t)(b * 80 + 8 + g * 9) * MNS + pix;

    float lg[9];
    float mx = -1e30f;
#pragma unroll
    for (int k = 0; k < 9; ++k) {
        const int dy = k / 3 - 1, dx = k % 3 - 1;
        const int ny = iy + dy, nx = ix + dx;
        const bool ok = ((unsigned)ny < 128u) && ((unsigned)nx < 128u);
        const float nb = ok ? bf2f(nbp[ny * WD + nx]) : 0.f;
        lg[k] = bf2f(mkp[(size_t)k * MNS]) + nb;
        mx = fmaxf(mx, lg[k]);
    }
    float s = 0.f;
#pragma unroll
    for (int k = 0; k < 9; ++k) { lg[k] = __expf(lg[k] - mx); s += lg[k]; }
    const float rs = 1.f / s;
#pragma unroll
    for (int k = 0; k < 9; ++k) lg[k] *= rs;   // OOB taps hit v==0 in LDS

    float* og = out + (size_t)(b * 256 + g * 32) * HW + pix;
#pragma unroll 2
    for (int o4 = 0; o4 < 8; ++o4) {
        const ushort4* vp = vt + o4 * PLS;
        float a0 = 0.f, a1 = 0.f, a2 = 0.f, a3 = 0.f;
#pragma unroll
        for (int k = 0; k < 9; ++k) {
            const int slot = (cy + k / 3) * PRS + (cx + k % 3);
            const ushort4 vv = vp[slot];
            a0 = fmaf(lg[k], bf2f(vv.x), a0);
            a1 = fmaf(lg[k], bf2f(vv.y), a1);
            a2 = fmaf(lg[k], bf2f(vv.z), a2);
            a3 = fmaf(lg[k], bf2f(vv.w), a3);
        }
        __builtin_nontemporal_store(a0, og + (size_t)(o4 * 4 + 0) * HW);
        __builtin_nontemporal_store(a1, og + (size_t)(o4 * 4 + 1) * HW);
        __builtin_nontemporal_store(a2, og + (size_t)(o4 * 4 + 2) * HW);
        __builtin_nontemporal_store(a3, og + (size_t)(o4 * 4 + 3) * HW);
    }
}

extern "C" void kernel_launch(void* const* d_in, const int* in_sizes, int n_in,
                              void* d_out, int out_size, void* d_ws, size_t ws_size,
                              hipStream_t stream)
{
    const float* x   = (const float*)d_in[0];
    const float* w1  = (const float*)d_in[1];
    const float* b1  = (const float*)d_in[2];
    const float* g1  = (const float*)d_in[3];
    const float* be1 = (const float*)d_in[4];
    const float* m1  = (const float*)d_in[5];
    const float* v1  = (const float*)d_in[6];
    const float* w2  = (const float*)d_in[7];
    const float* b2  = (const float*)d_in[8];
    const float* g2  = (const float*)d_in[9];
    const float* be2 = (const float*)d_in[10];
    const float* m2  = (const float*)d_in[11];
    const float* v2  = (const float*)d_in[12];
    const float* wv  = (const float*)d_in[13];

    float* out = (float*)d_out;
    unsigned short* mn = (unsigned short*)d_ws;   // 2*80*MNS bf16 = 5.3 MB

    dim3 blk(256);
    dim3 g1d(HW / 256, 16);        // 1024 blocks
    dim3 g2d(16, 64);              // (bg, tile): id%8==g -> XCD locality

    hipLaunchKernelGGL(la_k1, g1d, blk, 0, stream,
                       x, w1, b1, g1, be1, m1, v1, w2, b2, g2, be2, m2, v2, mn);
    hipLaunchKernelGGL(la_k2, g2d, blk, 0, stream, x, wv, mn, out);
}